// Round 13
// baseline (380.906 us; speedup 1.0000x reference)
//
#include <hip/hip_runtime.h>
#include <math.h>

#define BB   4
#define NN   8192
#define BN   (BB*NN)       // 32768 points per cloud-set; 8 clouds of 8192 total
#define KNN  10
#define G    32            // grid cells per dim
#define NCELLS (G*G*G)     // 32768 cells per cloud
#define GRID_LO (-5.0f)
#define H    0.3125f       // 10/32
#define INV_H 3.2f
#define RCAP 2             // rho<=2 region; beyond -> brute overflow

#define SEPS    5.9604645e-8f        // slamch('E') = 2^-24
#define SEPS2   (SEPS*SEPS)
#define SSAFMIN 1.1754944e-38f

__device__ __forceinline__ int cellc(float v) {
    int c = (int)floorf((v - GRID_LO) * INV_H);
    return min(G - 1, max(0, c));
}

// ---------------------------------------------------------------------------
// Kernel A: build P4[8][8192] = (x,y,z, bitcast orig-idx); clouds 0-3 = gt
// batches, 4-7 = pred[idx12] batches. Histogram cells + zero accumulators.
// ---------------------------------------------------------------------------
__global__ __launch_bounds__(256) void prep_kernel(
    const float* __restrict__ gt, const float* __restrict__ pred,
    const unsigned* __restrict__ idxw, float4* __restrict__ P4,
    int* __restrict__ hist, float* __restrict__ accum,
    unsigned* __restrict__ counter, int* __restrict__ ovf_count)
{
    __shared__ int s_is32;
    int tid = threadIdx.x;
    if (tid == 0) s_is32 = 0;
    __syncthreads();
    if (idxw[2*tid + 1] != 0u) s_is32 = 1;   // int64 => all high words 0
    __syncthreads();
    bool is64 = (s_is32 == 0);

    if (blockIdx.x == 0 && tid == 0) {
        *accum = 0.0f; *counter = 0u; *ovf_count = 0;
    }

    int point = blockIdx.x * 256 + tid;        // 0 .. 2*BN-1
    int pair = point >> 13;                    // 0..7
    int r    = point & (NN - 1);               // idx within cloud
    float x, y, z;
    if (point < BN) {
        const float* s = gt + (size_t)point*3;
        x = s[0]; y = s[1]; z = s[2];
    } else {
        int rr = point - BN;
        int b = rr >> 13;
        unsigned idx = is64 ? idxw[2*(size_t)rr] : idxw[rr];
        const float* s = pred + ((size_t)b*NN + idx)*3;
        x = s[0]; y = s[1]; z = s[2];
    }
    P4[point] = make_float4(x, y, z, __int_as_float(r));
    int cell = (cellc(z)*G + cellc(y))*G + cellc(x);
    atomicAdd(&hist[(size_t)pair*NCELLS + cell], 1);
}

// ---------------------------------------------------------------------------
// Kernel B: per-cloud exclusive scan -> combo[c] = int2(start, count).
// ---------------------------------------------------------------------------
__global__ __launch_bounds__(1024) void scan_kernel(
    const int* __restrict__ hist, int2* __restrict__ combo)
{
    int cloud = blockIdx.x;
    int tid = threadIdx.x;
    int lane = tid & 63, wid = tid >> 6;
    const int* h = hist + (size_t)cloud * NCELLS;
    int2* cb = combo + (size_t)cloud * NCELLS;

    int loc[32];
    int base = tid * 32;
    const int4* h4 = (const int4*)(h + base);
    int sum = 0;
    #pragma unroll
    for (int i = 0; i < 8; ++i) {
        int4 a = h4[i];
        loc[4*i+0] = a.x; loc[4*i+1] = a.y; loc[4*i+2] = a.z; loc[4*i+3] = a.w;
        sum += a.x + a.y + a.z + a.w;
    }
    // inclusive wave scan of sums
    int v = sum;
    #pragma unroll
    for (int off = 1; off < 64; off <<= 1) {
        int o = __shfl_up(v, off, 64);
        if (lane >= off) v += o;
    }
    __shared__ int ws[16], wsx[16];
    if (lane == 63) ws[wid] = v;
    __syncthreads();
    if (tid < 16) {
        int acc = 0;
        for (int i = 0; i < tid; ++i) acc += ws[i];
        wsx[tid] = acc;
    }
    __syncthreads();
    int run = (v - sum) + wsx[wid];            // exclusive prefix for this thread

    int4* cb4 = (int4*)(cb + base);            // 2 cells per int4 store
    #pragma unroll
    for (int i = 0; i < 16; ++i) {
        int4 o;
        o.x = run; o.y = loc[2*i];     run += loc[2*i];
        o.z = run; o.w = loc[2*i+1];   run += loc[2*i+1];
        cb4[i] = o;
    }
}

// ---------------------------------------------------------------------------
// Kernel C: scatter points into cell-sorted S.
// ---------------------------------------------------------------------------
__global__ __launch_bounds__(256) void scatter_kernel(
    const float4* __restrict__ P4, int* __restrict__ hist,
    const int2* __restrict__ combo, float4* __restrict__ S)
{
    int point = blockIdx.x * 256 + threadIdx.x;
    float4 p = P4[point];
    int pair = point >> 13;
    int cell = (cellc(p.z)*G + cellc(p.y))*G + cellc(p.x);
    int old = atomicSub(&hist[(size_t)pair*NCELLS + cell], 1);
    int pos = combo[(size_t)pair*NCELLS + cell].x + old - 1;
    S[(size_t)pair*NN + pos] = p;
}

// ---------------------------------------------------------------------------
// LAPACK ssyevd 3x3 path: ssytrd('L') + sorgtr + ssteqr('V'). Sign-faithful.
// (verified absmax 0.0 in rounds 2-12 — do not touch)
// ---------------------------------------------------------------------------
__device__ __forceinline__ float f_sign(float a, float b) {
    return copysignf(a, b);
}
__device__ __forceinline__ float slapy2(float x, float y) {
#pragma clang fp contract(off)
    float xa = fabsf(x), ya = fabsf(y);
    float w = fmaxf(xa, ya), z = fminf(xa, ya);
    if (z == 0.0f) return w;
    float t = z / w;
    return w * __fsqrt_rn(1.0f + t*t);
}
__device__ __forceinline__ void slartg_(float f, float g, float* cs, float* sn, float* r) {
#pragma clang fp contract(off)
    if (g == 0.0f)      { *cs = 1.0f; *sn = 0.0f; *r = f; }
    else if (f == 0.0f) { *cs = 0.0f; *sn = f_sign(1.0f, g); *r = fabsf(g); }
    else {
        float f1 = fabsf(f);
        float d = __fsqrt_rn(f*f + g*g);
        float p = 1.0f / d;
        *cs = f1 * p;
        *sn = g * f_sign(p, f);
        *r  = f_sign(d, f);
    }
}
__device__ void slaev2_(float a, float b, float c,
                        float* rt1, float* rt2, float* cs1, float* sn1) {
#pragma clang fp contract(off)
    float sm = a + c, df = a - c;
    float adf = fabsf(df);
    float tb = b + b;
    float ab = fabsf(tb);
    float acmx, acmn;
    if (fabsf(a) > fabsf(c)) { acmx = a; acmn = c; } else { acmx = c; acmn = a; }
    float rt;
    if (adf > ab)      { float t = ab/adf; rt = adf*__fsqrt_rn(1.0f + t*t); }
    else if (adf < ab) { float t = adf/ab; rt = ab*__fsqrt_rn(1.0f + t*t); }
    else               { rt = ab*__fsqrt_rn(2.0f); }
    int sgn1;
    if (sm < 0.0f)      { *rt1 = 0.5f*(sm - rt); sgn1 = -1;
                          *rt2 = (acmx / *rt1)*acmn - (b / *rt1)*b; }
    else if (sm > 0.0f) { *rt1 = 0.5f*(sm + rt); sgn1 = 1;
                          *rt2 = (acmx / *rt1)*acmn - (b / *rt1)*b; }
    else                { *rt1 = 0.5f*rt; *rt2 = -0.5f*rt; sgn1 = 1; }
    float cs; int sgn2;
    if (df >= 0.0f) { cs = df + rt; sgn2 = 1; } else { cs = df - rt; sgn2 = -1; }
    float acs = fabsf(cs);
    float c1, s1;
    if (acs > ab) { float ct = -tb/cs; s1 = 1.0f/__fsqrt_rn(1.0f + ct*ct); c1 = ct*s1; }
    else {
        if (ab == 0.0f) { c1 = 1.0f; s1 = 0.0f; }
        else { float tn = -cs/tb; c1 = 1.0f/__fsqrt_rn(1.0f + tn*tn); s1 = tn*c1; }
    }
    if (sgn1 == sgn2) { float tn = c1; c1 = -s1; s1 = tn; }
    *cs1 = c1; *sn1 = s1;
}

__device__ void eigh3_smallest(float c00, float c01, float c02,
                               float c11, float c12, float c22, float nv[3])
{
#pragma clang fp contract(off)
    // ---- ssytrd('L') ----
    float d[4], e[3], z[4][4];
    float tau1, v2 = 0.0f;
    float e1, d2, d3, e2;
    float alpha = c01, x = c02;
    if (x == 0.0f) {
        tau1 = 0.0f; e1 = alpha;
        d2 = c11; d3 = c22; e2 = c12;
    } else {
        float beta = -f_sign(slapy2(alpha, fabsf(x)), alpha);
        tau1 = (beta - alpha) / beta;
        v2 = x / (alpha - beta);
        e1 = beta;
        float w1 = tau1*(c11 + c12*v2);
        float w2 = tau1*(c12 + c22*v2);
        float al = -0.5f*tau1*(w1 + w2*v2);
        w1 = w1 + al;
        w2 = w2 + al*v2;
        d2 = (c11 - w1) - w1;
        e2 = (c12 - v2*w1) - w2;
        d3 = (c22 - v2*w2) - w2*v2;
    }
    d[1] = c00; d[2] = d2; d[3] = d3;
    e[1] = e1;  e[2] = e2;
    z[1][1] = 1.0f; z[1][2] = 0.0f; z[1][3] = 0.0f;
    z[2][1] = 0.0f; z[3][1] = 0.0f;
    z[2][2] = 1.0f - tau1;
    float mtv = -tau1*v2;
    z[2][3] = mtv; z[3][2] = mtv;
    z[3][3] = 1.0f + mtv*v2;

    // ---- ssteqr('V', 3) ----
    const int n = 3, nm1 = 2;
    int l1 = 1, jtot = 0;
    const int nmaxit = 90;
    float cw[3], sw[3];
    int guard = 0;
    while (guard++ < 64) {
        if (l1 > n) break;
        if (l1 > 1) e[l1-1] = 0.0f;
        int m = n;
        if (l1 <= nm1) {
            for (int mi = l1; mi <= nm1; ++mi) {
                float tst = fabsf(e[mi]);
                if (tst == 0.0f) { m = mi; break; }
                if (tst <= (__fsqrt_rn(fabsf(d[mi]))*__fsqrt_rn(fabsf(d[mi+1])))*SEPS) {
                    e[mi] = 0.0f; m = mi; break;
                }
            }
        }
        int l = l1;
        int lsv = l, lend = m, lendsv = lend;
        l1 = m + 1;
        if (lend == l) continue;
        if (fabsf(d[lend]) < fabsf(d[l])) { lend = lsv; l = lendsv; }

        if (lend > l) {
            // QL
            while (true) {
                int m_ = lend;
                if (l != lend) {
                    for (int mi = l; mi <= lend-1; ++mi) {
                        float em = e[mi];
                        float tst = em*em;
                        if (tst <= (SEPS2*fabsf(d[mi]))*fabsf(d[mi+1]) + SSAFMIN) { m_ = mi; break; }
                    }
                }
                if (m_ < lend) e[m_] = 0.0f;
                float p = d[l];
                if (m_ == l) {
                    d[l] = p; l = l + 1;
                    if (l <= lend) continue; else break;
                }
                if (m_ == l + 1) {
                    float rt1, rt2, cc, ss;
                    slaev2_(d[l], e[l], d[l+1], &rt1, &rt2, &cc, &ss);
                    for (int i = 1; i <= 3; ++i) {
                        float tmp = z[i][l+1];
                        z[i][l+1] = cc*tmp - ss*z[i][l];
                        z[i][l]   = ss*tmp + cc*z[i][l];
                    }
                    d[l] = rt1; d[l+1] = rt2; e[l] = 0.0f;
                    l = l + 2;
                    if (l <= lend) continue; else break;
                }
                if (jtot == nmaxit) break;
                jtot++;
                float g = (d[l+1] - p) / (2.0f*e[l]);
                float r = slapy2(g, 1.0f);
                g = d[m_] - p + (e[l] / (g + f_sign(r, g)));
                float s = 1.0f, c = 1.0f;
                p = 0.0f;
                for (int i = m_-1; i >= l; --i) {
                    float f = s*e[i];
                    float b = c*e[i];
                    slartg_(g, f, &c, &s, &r);
                    if (i != m_-1) e[i+1] = r;
                    g = d[i+1] - p;
                    r = (d[i] - g)*s + (2.0f*c)*b;
                    p = s*r;
                    d[i+1] = g + p;
                    g = c*r - b;
                    cw[i] = c; sw[i] = -s;
                }
                for (int j = m_-1; j >= l; --j) {
                    float cc = cw[j], ss = sw[j];
                    for (int i = 1; i <= 3; ++i) {
                        float tmp = z[i][j+1];
                        z[i][j+1] = cc*tmp - ss*z[i][j];
                        z[i][j]   = ss*tmp + cc*z[i][j];
                    }
                }
                d[l] = d[l] - p;
                e[l] = g;
            }
        } else {
            // QR
            while (true) {
                int m_ = lend;
                if (l != lend) {
                    for (int mi = l; mi >= lend+1; --mi) {
                        float em = e[mi-1];
                        float tst = em*em;
                        if (tst <= (SEPS2*fabsf(d[mi]))*fabsf(d[mi-1]) + SSAFMIN) { m_ = mi; break; }
                    }
                }
                if (m_ > lend) e[m_-1] = 0.0f;
                float p = d[l];
                if (m_ == l) {
                    d[l] = p; l = l - 1;
                    if (l >= lend) continue; else break;
                }
                if (m_ == l - 1) {
                    float rt1, rt2, cc, ss;
                    slaev2_(d[l-1], e[l-1], d[l], &rt1, &rt2, &cc, &ss);
                    for (int i = 1; i <= 3; ++i) {
                        float tmp = z[i][l];
                        z[i][l]   = cc*tmp - ss*z[i][l-1];
                        z[i][l-1] = ss*tmp + cc*z[i][l-1];
                    }
                    d[l-1] = rt1; d[l] = rt2; e[l-1] = 0.0f;
                    l = l - 2;
                    if (l >= lend) continue; else break;
                }
                if (jtot == nmaxit) break;
                jtot++;
                float g = (d[l-1] - p) / (2.0f*e[l-1]);
                float r = slapy2(g, 1.0f);
                g = d[m_] - p + (e[l-1] / (g + f_sign(r, g)));
                float s = 1.0f, c = 1.0f;
                p = 0.0f;
                for (int i = m_; i <= l-1; ++i) {
                    float f = s*e[i];
                    float b = c*e[i];
                    slartg_(g, f, &c, &s, &r);
                    if (i != m_) e[i-1] = r;
                    g = d[i] - p;
                    r = (d[i+1] - g)*s + (2.0f*c)*b;
                    p = s*r;
                    d[i] = g + p;
                    g = c*r - b;
                    cw[i] = c; sw[i] = s;
                }
                for (int j = m_; j <= l-1; ++j) {
                    float cc = cw[j], ss = sw[j];
                    for (int i = 1; i <= 3; ++i) {
                        float tmp = z[i][j+1];
                        z[i][j+1] = cc*tmp - ss*z[i][j];
                        z[i][j]   = ss*tmp + cc*z[i][j];
                    }
                }
                d[l] = d[l] - p;
                e[l-1] = g;
            }
        }
    }
    for (int ii = 2; ii <= 3; ++ii) {
        int i = ii - 1, k = i;
        float p = d[i];
        for (int j = ii; j <= 3; ++j) if (d[j] < p) { k = j; p = d[j]; }
        if (k != i) {
            d[k] = d[i]; d[i] = p;
            for (int r2 = 1; r2 <= 3; ++r2) {
                float t = z[r2][i]; z[r2][i] = z[r2][k]; z[r2][k] = t;
            }
        }
    }
    nv[0] = z[1][1]; nv[1] = z[2][1]; nv[2] = z[3][1];
}

// Shared epilogue math: covariance of the sorted 10-neighborhood + eigh.
__device__ void normal_compute(const float4* __restrict__ cl,
                               const unsigned long long keys[KNN],
                               float nv[3])
{
#pragma clang fp contract(off)
    float px[KNN], py[KNN], pz[KNN];
    float sx = 0.f, sy = 0.f, sz = 0.f;
    #pragma unroll
    for (int s = 0; s < KNN; ++s) {
        int ni = (int)(unsigned)(keys[s] & 0xFFFFFFFFull);
        float4 np = cl[ni];
        px[s] = np.x; py[s] = np.y; pz[s] = np.z;
        sx = sx + px[s]; sy = sy + py[s]; sz = sz + pz[s];
    }
    float mx = sx / 10.0f, my = sy / 10.0f, mz = sz / 10.0f;
    float c00=0.f,c01=0.f,c02=0.f,c11=0.f,c12=0.f,c22=0.f;
    #pragma unroll
    for (int s = 0; s < KNN; ++s) {
        float dx = px[s]-mx, dy = py[s]-my, dz = pz[s]-mz;
        c00 = c00 + dx*dx; c01 = c01 + dx*dy; c02 = c02 + dx*dz;
        c11 = c11 + dy*dy; c12 = c12 + dy*dz; c22 = c22 + dz*dz;
    }
    c00 = c00/10.0f; c01 = c01/10.0f; c02 = c02/10.0f;
    c11 = c11/10.0f; c12 = c12/10.0f; c22 = c22/10.0f;
    eigh3_smallest(c00, c01, c02, c11, c12, c22, nv);
}

// candidate insert (strict u64 key compare == top_k (d, idx) tie semantics)
#define PROC(p) do { \
    float ddx = qx - (p).x, ddy = qy - (p).y, ddz = qz - (p).z; \
    float dd = fmaf(ddz, ddz, fmaf(ddy, ddy, ddx*ddx)); \
    unsigned long long key = \
        ((unsigned long long)__float_as_uint(dd) << 32) | \
        (unsigned)__float_as_int((p).w); \
    if (key < k9) { \
        unsigned long long ck = key; \
        _Pragma("unroll") \
        for (int s = 0; s < KNN; ++s) { \
            unsigned long long ok2 = keys[s]; \
            bool sw = ok2 > ck; \
            keys[s] = sw ? ck : ok2; \
            ck      = sw ? ok2 : ck; \
        } \
        k9 = keys[KNN-1]; \
        worst = __uint_as_float((unsigned)(k9 >> 32)); \
    } \
} while (0)

// stream a contiguous candidate segment [b, b+n) of S — 2 loads in flight
// (4-wide tried in R11: VGPR 48->68, scratch spills, WRITE_SIZE 2.2->12 MB,
//  knn_main 130->170 us. This kernel is at register capacity; keep 2-wide.)
#define SEGPROC(b, n) do { \
    int _j = (b), _je = (b) + (n); \
    for (; _j + 2 <= _je; _j += 2) { \
        float4 _p0 = cs[_j]; float4 _p1 = cs[_j+1]; \
        PROC(_p0); PROC(_p1); \
    } \
    if (_j < _je) { float4 _p0 = cs[_j]; PROC(_p0); } \
} while (0)

// ---------------------------------------------------------------------------
// Kernel D: grid 10-NN, 1 lane/query, static segment descriptors in named
// scalars. R13 consolidation: phase 1 = 9 rows at x+/-2 (absorbs R12's 18
// isolated cells into the same row loads: rows contiguous in S -> still 2
// directory loads/row; extra candidates are a superset -> cannot change the
// selected top-10). Phase 2 = only the 16 outer rows (max(|dz|,|dy|)==2).
// Descriptors 68->50 loads, segments 43->25, live ints 68->32 (less pressure
// -> compiler can batch loads). Skip test H^2>worst unchanged (outside the
// widened phase-1 region min gap is still H). Resolved test (2H)^2>worst
// unchanged (phase1 U phase2 covers the full rho<=2 region).
// ---------------------------------------------------------------------------
__global__ __launch_bounds__(256) void knn_main_kernel(
    const float4* __restrict__ P4, const float4* __restrict__ S,
    const int2* __restrict__ combo, float* __restrict__ Nrm,
    int* __restrict__ ovf, unsigned long long* __restrict__ ovf_key,
    int* __restrict__ ovf_count)
{
    int tidg = blockIdx.x * 256 + threadIdx.x;  // 0..65535
    int pair = tidg >> 13;                      // 8 clouds
    int spos = tidg & (NN - 1);                 // sorted position
    const float4* __restrict__ cl = P4 + (size_t)pair * NN;
    const float4* __restrict__ cs = S  + (size_t)pair * NN;
    const int2*   __restrict__ cb = combo + (size_t)pair * NCELLS;

    float4 q = cs[spos];
    float qx = q.x, qy = q.y, qz = q.z;
    int qi = __float_as_int(q.w);               // original index in cloud
    int qcx = cellc(qx), qcy = cellc(qy), qcz = cellc(qz);

    unsigned long long keys[KNN];
    #pragma unroll
    for (int s = 0; s < KNN; ++s) keys[s] = 0xFFFFFFFFFFFFFFFFull;
    unsigned long long k9 = keys[KNN-1];
    float worst = __uint_as_float(0xFFFFFFFFu); // NaN: all strict-> tests false

    // x-range for ALL rows: qcx +/- 2 (clamped)
    int x0 = max(qcx - 2, 0), x1 = min(qcx + 2, G - 1);

    // ---- phase 1: |dz|<=1, |dy|<=1 rows at x+/-2 (9 rows, no pruning) ----
#define P1LOAD(i, DZ, DY) \
    int rb##i = 0, re##i = 0; \
    { int zz = qcz + (DZ), yy = qcy + (DY); \
      if ((unsigned)zz < G && (unsigned)yy < G) { \
          int cbase = (zz*G + yy)*G; \
          int2 a = cb[cbase + x0]; \
          int2 b = cb[cbase + x1]; \
          rb##i = a.x; re##i = b.x + b.y; } }
    P1LOAD(0,-1,-1) P1LOAD(1,-1,0) P1LOAD(2,-1,1)
    P1LOAD(3, 0,-1) P1LOAD(4, 0,0) P1LOAD(5, 0,1)
    P1LOAD(6, 1,-1) P1LOAD(7, 1,0) P1LOAD(8, 1,1)
#undef P1LOAD
#define P1GO(i) SEGPROC(rb##i, re##i - rb##i);
    P1GO(0) P1GO(1) P1GO(2) P1GO(3) P1GO(4) P1GO(5) P1GO(6) P1GO(7) P1GO(8)
#undef P1GO

    // ---- phase 2: the 16 outer rows, max(|dz|,|dy|)==2 (skip iff H^2>worst) ----
    bool skip = (H*H > worst);                  // NaN-safe: NaN -> walk shell
    {
#define S2ROW(i, DZ, DY) \
        int sb##i = 0, sn##i = 0; \
        if (!skip) { int zz = qcz + (DZ), yy = qcy + (DY); \
          if ((unsigned)zz < G && (unsigned)yy < G) { \
              float loy = fmaf((float)yy, H, GRID_LO); \
              float loz = fmaf((float)zz, H, GRID_LO); \
              float py = fmaxf(0.0f, fmaxf(loy - qy, qy - (loy + H))); \
              float pz = fmaxf(0.0f, fmaxf(loz - qz, qz - (loz + H))); \
              float pyz = fmaf(pz, pz, py*py); \
              if (!(pyz > worst)) { \
                  int cbase = (zz*G + yy)*G; \
                  int2 a = cb[cbase + x0]; \
                  int2 b = cb[cbase + x1]; \
                  sb##i = a.x; sn##i = (b.x + b.y) - a.x; } } }
        S2ROW( 0,-2,-2) S2ROW( 1,-2,-1) S2ROW( 2,-2, 0) S2ROW( 3,-2, 1) S2ROW( 4,-2, 2)
        S2ROW( 5, 2,-2) S2ROW( 6, 2,-1) S2ROW( 7, 2, 0) S2ROW( 8, 2, 1) S2ROW( 9, 2, 2)
        S2ROW(10,-1,-2) S2ROW(11,-1, 2) S2ROW(12, 0,-2) S2ROW(13, 0, 2)
        S2ROW(14, 1,-2) S2ROW(15, 1, 2)
#undef S2ROW
#define S2GO(i) SEGPROC(sb##i, sn##i);
        S2GO(0) S2GO(1) S2GO(2) S2GO(3) S2GO(4) S2GO(5) S2GO(6) S2GO(7)
        S2GO(8) S2GO(9) S2GO(10) S2GO(11) S2GO(12) S2GO(13) S2GO(14) S2GO(15)
#undef S2GO
    }

    // resolved iff cells beyond the rho<=2 region (gap >= 2H) cannot contribute
    float bf = (float)RCAP * H;
    bool resolved = (bf*bf > worst);            // strict; NaN (unfilled) -> false
    if (resolved) {
        float nv[3];
        normal_compute(cl, keys, nv);
        float* o = Nrm + ((size_t)pair*NN + qi)*3;
        o[0] = nv[0]; o[1] = nv[1]; o[2] = nv[2];
    } else {
        int pos = atomicAdd(ovf_count, 1);
        ovf[pos] = (pair << 13) | qi;
        ovf_key[pos] = k9;      // partial 10th-best: valid upper bound on true
    }                           // 10th key (subset 10th >= full-set 10th)
}

// ---------------------------------------------------------------------------
// Kernel D2: brute-force overflow, one query per block (256 thr = 4 waves).
// The main-phase 10th-best key is a proven upper bound on the true 10th
// key, so candidates with dd > bound_d are provably not in the top-10 and
// skip the insert chain entirely. bound_d = NaN for unfilled lists -> gate
// passes everything (NaN-safe !(dd > bound_d)).
// ---------------------------------------------------------------------------
#define BRUTE_BLOCKS 4096
__global__ __launch_bounds__(256) void brute_kernel(
    const float4* __restrict__ P4, const int* __restrict__ ovf,
    const unsigned long long* __restrict__ ovf_key,
    const int* __restrict__ ovf_count, float* __restrict__ Nrm)
{
    __shared__ unsigned long long wl[4][KNN];
    int tid = threadIdx.x;
    int lane = tid & 63;
    int wid = tid >> 6;
    int count = *ovf_count;

    for (int oi = blockIdx.x; oi < count; oi += BRUTE_BLOCKS) {
        int rec = ovf[oi];
        unsigned long long bound = ovf_key[oi];
        float bound_d = __uint_as_float((unsigned)(bound >> 32)); // NaN if unfilled
        int pair = rec >> 13;
        int qi = rec & (NN - 1);
        const float4* __restrict__ cl = P4 + (size_t)pair * NN;
        float4 q = cl[qi];
        float qx = q.x, qy = q.y, qz = q.z;

        unsigned long long keys[KNN];
        #pragma unroll
        for (int s = 0; s < KNN; ++s) keys[s] = 0xFFFFFFFFFFFFFFFFull;
        unsigned long long k9 = keys[KNN-1];

        // per-lane scan with bound gate; ties at dd==bound_d pass (exact)
#define BPROC(p, jj) do { \
        float ddx = qx - (p).x, ddy = qy - (p).y, ddz = qz - (p).z; \
        float dd = fmaf(ddz, ddz, fmaf(ddy, ddy, ddx*ddx)); \
        if (!(dd > bound_d)) { \
            unsigned long long key = \
                ((unsigned long long)__float_as_uint(dd) << 32) | (unsigned)(jj); \
            if (key < k9) { \
                unsigned long long ck = key; \
                _Pragma("unroll") \
                for (int s = 0; s < KNN; ++s) { \
                    unsigned long long ok2 = keys[s]; \
                    bool sw = ok2 > ck; \
                    keys[s] = sw ? ck : ok2; \
                    ck      = sw ? ok2 : ck; \
                } \
                k9 = keys[KNN-1]; \
            } \
        } \
    } while (0)
        #pragma unroll 1
        for (int j = tid; j < NN; j += 512) {   // 16 iterations, 2 loads each
            float4 p0 = cl[j];
            float4 p1 = cl[j + 256];
            BPROC(p0, j);
            BPROC(p1, j + 256);
        }
#undef BPROC

        // in-wave tree merge -> every lane holds its wave's top-10
        #pragma unroll
        for (int m = 1; m < 64; m <<= 1) {
            unsigned long long other[KNN];
            #pragma unroll
            for (int s = 0; s < KNN; ++s)
                other[s] = __shfl_xor(keys[s], m);  // snapshot before inserts
            #pragma unroll
            for (int s = 0; s < KNN; ++s) {
                unsigned long long key = other[s];
                if (key < k9) {
                    unsigned long long ck = key;
                    #pragma unroll
                    for (int t = 0; t < KNN; ++t) {
                        unsigned long long ok2 = keys[t];
                        bool sw = ok2 > ck;
                        keys[t] = sw ? ck : ok2;
                        ck      = sw ? ok2 : ck;
                    }
                    k9 = keys[KNN-1];
                }
            }
        }

        // cross-wave merge via LDS (4 sorted lists)
        if (lane == 0) {
            #pragma unroll
            for (int s = 0; s < KNN; ++s) wl[wid][s] = keys[s];
        }
        __syncthreads();
        if (wid == 0) {
            for (int w2 = 1; w2 < 4; ++w2) {
                #pragma unroll
                for (int s = 0; s < KNN; ++s) {
                    unsigned long long key = wl[w2][s];
                    if (key >= k9) break;       // lists sorted ascending
                    unsigned long long ck = key;
                    #pragma unroll
                    for (int t = 0; t < KNN; ++t) {
                        unsigned long long ok2 = keys[t];
                        bool sw = ok2 > ck;
                        keys[t] = sw ? ck : ok2;
                        ck      = sw ? ok2 : ck;
                    }
                    k9 = keys[KNN-1];
                }
            }
            if (lane == 0) {
                float nv[3];
                normal_compute(cl, keys, nv);
                float* o = Nrm + ((size_t)pair*NN + qi)*3;
                o[0] = nv[0]; o[1] = nv[1]; o[2] = nv[2];
            }
        }
        __syncthreads();                        // protect wl for next query
    }
}

// ---------------------------------------------------------------------------
// Kernel E: per-point 1 - cos, block partial sums, device-scope atomic
// accumulate; last block writes the mean.
// ---------------------------------------------------------------------------
__global__ __launch_bounds__(256) void loss_final_kernel(
    const float* __restrict__ Nrm, float* __restrict__ accum,
    unsigned* __restrict__ counter, float* __restrict__ out)
{
    int tid = threadIdx.x;
    int i = blockIdx.x * 256 + tid;            // 0..BN-1
    const float* g = Nrm + (size_t)i*3;
    const float* p = Nrm + ((size_t)BN + i)*3;
    float gx=g[0], gy=g[1], gz=g[2];
    float hx=p[0], hy=p[1], hz=p[2];
    float dot = fmaf(gx,hx,fmaf(gy,hy,gz*hz));
    float ng  = sqrtf(fmaf(gx,gx,fmaf(gy,gy,gz*gz)));
    float nh  = sqrtf(fmaf(hx,hx,fmaf(hy,hy,hz*hz)));
    float den = fmaxf(ng*nh, 1e-8f);
    float v = 1.0f - dot/den;

    __shared__ float red[256];
    red[tid] = v;
    __syncthreads();
    for (int s = 128; s > 0; s >>= 1) {
        if (tid < s) red[tid] += red[tid+s];
        __syncthreads();
    }
    if (tid == 0) {
        atomicAdd(accum, red[0]);
        __threadfence();
        unsigned old = atomicAdd(counter, 1u);
        if (old == (unsigned)(BN/256 - 1)) {
            float tot = atomicAdd(accum, 0.0f);
            out[0] = tot * (1.0f/(float)BN);
        }
    }
}

// ---------------------------------------------------------------------------
extern "C" void kernel_launch(void* const* d_in, const int* in_sizes, int n_in,
                              void* d_out, int out_size, void* d_ws, size_t ws_size,
                              hipStream_t stream)
{
    (void)in_sizes; (void)n_in; (void)out_size; (void)ws_size;
    const float*    gt   = (const float*)d_in[0];
    const float*    pred = (const float*)d_in[1];
    const unsigned* idxw = (const unsigned*)d_in[2];
    float* out = (float*)d_out;

    char* w = (char*)d_ws;
    float4* P4   = (float4*)w;                         w += (size_t)2*BN*16;   // 1 MB
    float4* S    = (float4*)w;                         w += (size_t)2*BN*16;   // 1 MB
    int*    hist = (int*)w;                            w += (size_t)8*NCELLS*4;   // 1 MB
    int2*   combo = (int2*)w;                          w += (size_t)8*NCELLS*8;   // 2 MB
    float*  Nrm  = (float*)w;                          w += (size_t)2*BN*3*4;  // 0.75 MB
    float*  accum = (float*)w;                         w += 16;
    unsigned* counter = (unsigned*)(accum + 1);
    int*    ovf_count = (int*)(accum + 2);
    int*    ovf  = (int*)w;                            w += (size_t)2*BN*4;    // 0.25 MB
    unsigned long long* ovf_key = (unsigned long long*)w;  w += (size_t)2*BN*8; // 0.5 MB

    hipMemsetAsync(hist, 0, (size_t)8*NCELLS*4, stream);
    hipLaunchKernelGGL(prep_kernel,    dim3(2*BN/256), dim3(256),  0, stream,
                       gt, pred, idxw, P4, hist, accum, counter, ovf_count);
    hipLaunchKernelGGL(scan_kernel,    dim3(8),        dim3(1024), 0, stream,
                       hist, combo);
    hipLaunchKernelGGL(scatter_kernel, dim3(2*BN/256), dim3(256),  0, stream,
                       P4, hist, combo, S);
    hipLaunchKernelGGL(knn_main_kernel, dim3(2*BN/256), dim3(256), 0, stream,
                       P4, S, combo, Nrm, ovf, ovf_key, ovf_count);
    hipLaunchKernelGGL(brute_kernel,   dim3(BRUTE_BLOCKS), dim3(256), 0, stream,
                       P4, ovf, ovf_key, ovf_count, Nrm);
    hipLaunchKernelGGL(loss_final_kernel, dim3(BN/256), dim3(256), 0, stream,
                       Nrm, accum, counter, out);
}

// Round 14
// 344.126 us; speedup vs baseline: 1.1069x; 1.1069x over previous
//
#include <hip/hip_runtime.h>
#include <math.h>

#define BB   4
#define NN   8192
#define BN   (BB*NN)       // 32768 points per cloud-set; 8 clouds of 8192 total
#define KNN  10
#define G    32            // grid cells per dim
#define NCELLS (G*G*G)     // 32768 cells per cloud
#define GRID_LO (-5.0f)
#define H    0.3125f       // 10/32
#define INV_H 3.2f
#define RCAP 2             // rho<=2 region; beyond -> brute overflow

#define SEPS    5.9604645e-8f        // slamch('E') = 2^-24
#define SEPS2   (SEPS*SEPS)
#define SSAFMIN 1.1754944e-38f

__device__ __forceinline__ int cellc(float v) {
    int c = (int)floorf((v - GRID_LO) * INV_H);
    return min(G - 1, max(0, c));
}

// ---------------------------------------------------------------------------
// Kernel A: build P4[8][8192] = (x,y,z, bitcast orig-idx); clouds 0-3 = gt
// batches, 4-7 = pred[idx12] batches. Histogram cells + zero accumulators.
// ---------------------------------------------------------------------------
__global__ __launch_bounds__(256) void prep_kernel(
    const float* __restrict__ gt, const float* __restrict__ pred,
    const unsigned* __restrict__ idxw, float4* __restrict__ P4,
    int* __restrict__ hist, float* __restrict__ accum,
    unsigned* __restrict__ counter, int* __restrict__ ovf_count)
{
    __shared__ int s_is32;
    int tid = threadIdx.x;
    if (tid == 0) s_is32 = 0;
    __syncthreads();
    if (idxw[2*tid + 1] != 0u) s_is32 = 1;   // int64 => all high words 0
    __syncthreads();
    bool is64 = (s_is32 == 0);

    if (blockIdx.x == 0 && tid == 0) {
        *accum = 0.0f; *counter = 0u; *ovf_count = 0;
    }

    int point = blockIdx.x * 256 + tid;        // 0 .. 2*BN-1
    int pair = point >> 13;                    // 0..7
    int r    = point & (NN - 1);               // idx within cloud
    float x, y, z;
    if (point < BN) {
        const float* s = gt + (size_t)point*3;
        x = s[0]; y = s[1]; z = s[2];
    } else {
        int rr = point - BN;
        int b = rr >> 13;
        unsigned idx = is64 ? idxw[2*(size_t)rr] : idxw[rr];
        const float* s = pred + ((size_t)b*NN + idx)*3;
        x = s[0]; y = s[1]; z = s[2];
    }
    P4[point] = make_float4(x, y, z, __int_as_float(r));
    int cell = (cellc(z)*G + cellc(y))*G + cellc(x);
    atomicAdd(&hist[(size_t)pair*NCELLS + cell], 1);
}

// ---------------------------------------------------------------------------
// Kernel B: per-cloud exclusive scan -> combo[c] = int2(start, count).
// ---------------------------------------------------------------------------
__global__ __launch_bounds__(1024) void scan_kernel(
    const int* __restrict__ hist, int2* __restrict__ combo)
{
    int cloud = blockIdx.x;
    int tid = threadIdx.x;
    int lane = tid & 63, wid = tid >> 6;
    const int* h = hist + (size_t)cloud * NCELLS;
    int2* cb = combo + (size_t)cloud * NCELLS;

    int loc[32];
    int base = tid * 32;
    const int4* h4 = (const int4*)(h + base);
    int sum = 0;
    #pragma unroll
    for (int i = 0; i < 8; ++i) {
        int4 a = h4[i];
        loc[4*i+0] = a.x; loc[4*i+1] = a.y; loc[4*i+2] = a.z; loc[4*i+3] = a.w;
        sum += a.x + a.y + a.z + a.w;
    }
    // inclusive wave scan of sums
    int v = sum;
    #pragma unroll
    for (int off = 1; off < 64; off <<= 1) {
        int o = __shfl_up(v, off, 64);
        if (lane >= off) v += o;
    }
    __shared__ int ws[16], wsx[16];
    if (lane == 63) ws[wid] = v;
    __syncthreads();
    if (tid < 16) {
        int acc = 0;
        for (int i = 0; i < tid; ++i) acc += ws[i];
        wsx[tid] = acc;
    }
    __syncthreads();
    int run = (v - sum) + wsx[wid];            // exclusive prefix for this thread

    int4* cb4 = (int4*)(cb + base);            // 2 cells per int4 store
    #pragma unroll
    for (int i = 0; i < 16; ++i) {
        int4 o;
        o.x = run; o.y = loc[2*i];     run += loc[2*i];
        o.z = run; o.w = loc[2*i+1];   run += loc[2*i+1];
        cb4[i] = o;
    }
}

// ---------------------------------------------------------------------------
// Kernel C: scatter points into cell-sorted S.
// ---------------------------------------------------------------------------
__global__ __launch_bounds__(256) void scatter_kernel(
    const float4* __restrict__ P4, int* __restrict__ hist,
    const int2* __restrict__ combo, float4* __restrict__ S)
{
    int point = blockIdx.x * 256 + threadIdx.x;
    float4 p = P4[point];
    int pair = point >> 13;
    int cell = (cellc(p.z)*G + cellc(p.y))*G + cellc(p.x);
    int old = atomicSub(&hist[(size_t)pair*NCELLS + cell], 1);
    int pos = combo[(size_t)pair*NCELLS + cell].x + old - 1;
    S[(size_t)pair*NN + pos] = p;
}

// ---------------------------------------------------------------------------
// LAPACK ssyevd 3x3 path: ssytrd('L') + sorgtr + ssteqr('V'). Sign-faithful.
// (verified absmax 0.0 in rounds 2-13 — do not touch)
// ---------------------------------------------------------------------------
__device__ __forceinline__ float f_sign(float a, float b) {
    return copysignf(a, b);
}
__device__ __forceinline__ float slapy2(float x, float y) {
#pragma clang fp contract(off)
    float xa = fabsf(x), ya = fabsf(y);
    float w = fmaxf(xa, ya), z = fminf(xa, ya);
    if (z == 0.0f) return w;
    float t = z / w;
    return w * __fsqrt_rn(1.0f + t*t);
}
__device__ __forceinline__ void slartg_(float f, float g, float* cs, float* sn, float* r) {
#pragma clang fp contract(off)
    if (g == 0.0f)      { *cs = 1.0f; *sn = 0.0f; *r = f; }
    else if (f == 0.0f) { *cs = 0.0f; *sn = f_sign(1.0f, g); *r = fabsf(g); }
    else {
        float f1 = fabsf(f);
        float d = __fsqrt_rn(f*f + g*g);
        float p = 1.0f / d;
        *cs = f1 * p;
        *sn = g * f_sign(p, f);
        *r  = f_sign(d, f);
    }
}
__device__ void slaev2_(float a, float b, float c,
                        float* rt1, float* rt2, float* cs1, float* sn1) {
#pragma clang fp contract(off)
    float sm = a + c, df = a - c;
    float adf = fabsf(df);
    float tb = b + b;
    float ab = fabsf(tb);
    float acmx, acmn;
    if (fabsf(a) > fabsf(c)) { acmx = a; acmn = c; } else { acmx = c; acmn = a; }
    float rt;
    if (adf > ab)      { float t = ab/adf; rt = adf*__fsqrt_rn(1.0f + t*t); }
    else if (adf < ab) { float t = adf/ab; rt = ab*__fsqrt_rn(1.0f + t*t); }
    else               { rt = ab*__fsqrt_rn(2.0f); }
    int sgn1;
    if (sm < 0.0f)      { *rt1 = 0.5f*(sm - rt); sgn1 = -1;
                          *rt2 = (acmx / *rt1)*acmn - (b / *rt1)*b; }
    else if (sm > 0.0f) { *rt1 = 0.5f*(sm + rt); sgn1 = 1;
                          *rt2 = (acmx / *rt1)*acmn - (b / *rt1)*b; }
    else                { *rt1 = 0.5f*rt; *rt2 = -0.5f*rt; sgn1 = 1; }
    float cs; int sgn2;
    if (df >= 0.0f) { cs = df + rt; sgn2 = 1; } else { cs = df - rt; sgn2 = -1; }
    float acs = fabsf(cs);
    float c1, s1;
    if (acs > ab) { float ct = -tb/cs; s1 = 1.0f/__fsqrt_rn(1.0f + ct*ct); c1 = ct*s1; }
    else {
        if (ab == 0.0f) { c1 = 1.0f; s1 = 0.0f; }
        else { float tn = -cs/tb; c1 = 1.0f/__fsqrt_rn(1.0f + tn*tn); s1 = tn*c1; }
    }
    if (sgn1 == sgn2) { float tn = c1; c1 = -s1; s1 = tn; }
    *cs1 = c1; *sn1 = s1;
}

__device__ void eigh3_smallest(float c00, float c01, float c02,
                               float c11, float c12, float c22, float nv[3])
{
#pragma clang fp contract(off)
    // ---- ssytrd('L') ----
    float d[4], e[3], z[4][4];
    float tau1, v2 = 0.0f;
    float e1, d2, d3, e2;
    float alpha = c01, x = c02;
    if (x == 0.0f) {
        tau1 = 0.0f; e1 = alpha;
        d2 = c11; d3 = c22; e2 = c12;
    } else {
        float beta = -f_sign(slapy2(alpha, fabsf(x)), alpha);
        tau1 = (beta - alpha) / beta;
        v2 = x / (alpha - beta);
        e1 = beta;
        float w1 = tau1*(c11 + c12*v2);
        float w2 = tau1*(c12 + c22*v2);
        float al = -0.5f*tau1*(w1 + w2*v2);
        w1 = w1 + al;
        w2 = w2 + al*v2;
        d2 = (c11 - w1) - w1;
        e2 = (c12 - v2*w1) - w2;
        d3 = (c22 - v2*w2) - w2*v2;
    }
    d[1] = c00; d[2] = d2; d[3] = d3;
    e[1] = e1;  e[2] = e2;
    z[1][1] = 1.0f; z[1][2] = 0.0f; z[1][3] = 0.0f;
    z[2][1] = 0.0f; z[3][1] = 0.0f;
    z[2][2] = 1.0f - tau1;
    float mtv = -tau1*v2;
    z[2][3] = mtv; z[3][2] = mtv;
    z[3][3] = 1.0f + mtv*v2;

    // ---- ssteqr('V', 3) ----
    const int n = 3, nm1 = 2;
    int l1 = 1, jtot = 0;
    const int nmaxit = 90;
    float cw[3], sw[3];
    int guard = 0;
    while (guard++ < 64) {
        if (l1 > n) break;
        if (l1 > 1) e[l1-1] = 0.0f;
        int m = n;
        if (l1 <= nm1) {
            for (int mi = l1; mi <= nm1; ++mi) {
                float tst = fabsf(e[mi]);
                if (tst == 0.0f) { m = mi; break; }
                if (tst <= (__fsqrt_rn(fabsf(d[mi]))*__fsqrt_rn(fabsf(d[mi+1])))*SEPS) {
                    e[mi] = 0.0f; m = mi; break;
                }
            }
        }
        int l = l1;
        int lsv = l, lend = m, lendsv = lend;
        l1 = m + 1;
        if (lend == l) continue;
        if (fabsf(d[lend]) < fabsf(d[l])) { lend = lsv; l = lendsv; }

        if (lend > l) {
            // QL
            while (true) {
                int m_ = lend;
                if (l != lend) {
                    for (int mi = l; mi <= lend-1; ++mi) {
                        float em = e[mi];
                        float tst = em*em;
                        if (tst <= (SEPS2*fabsf(d[mi]))*fabsf(d[mi+1]) + SSAFMIN) { m_ = mi; break; }
                    }
                }
                if (m_ < lend) e[m_] = 0.0f;
                float p = d[l];
                if (m_ == l) {
                    d[l] = p; l = l + 1;
                    if (l <= lend) continue; else break;
                }
                if (m_ == l + 1) {
                    float rt1, rt2, cc, ss;
                    slaev2_(d[l], e[l], d[l+1], &rt1, &rt2, &cc, &ss);
                    for (int i = 1; i <= 3; ++i) {
                        float tmp = z[i][l+1];
                        z[i][l+1] = cc*tmp - ss*z[i][l];
                        z[i][l]   = ss*tmp + cc*z[i][l];
                    }
                    d[l] = rt1; d[l+1] = rt2; e[l] = 0.0f;
                    l = l + 2;
                    if (l <= lend) continue; else break;
                }
                if (jtot == nmaxit) break;
                jtot++;
                float g = (d[l+1] - p) / (2.0f*e[l]);
                float r = slapy2(g, 1.0f);
                g = d[m_] - p + (e[l] / (g + f_sign(r, g)));
                float s = 1.0f, c = 1.0f;
                p = 0.0f;
                for (int i = m_-1; i >= l; --i) {
                    float f = s*e[i];
                    float b = c*e[i];
                    slartg_(g, f, &c, &s, &r);
                    if (i != m_-1) e[i+1] = r;
                    g = d[i+1] - p;
                    r = (d[i] - g)*s + (2.0f*c)*b;
                    p = s*r;
                    d[i+1] = g + p;
                    g = c*r - b;
                    cw[i] = c; sw[i] = -s;
                }
                for (int j = m_-1; j >= l; --j) {
                    float cc = cw[j], ss = sw[j];
                    for (int i = 1; i <= 3; ++i) {
                        float tmp = z[i][j+1];
                        z[i][j+1] = cc*tmp - ss*z[i][j];
                        z[i][j]   = ss*tmp + cc*z[i][j];
                    }
                }
                d[l] = d[l] - p;
                e[l] = g;
            }
        } else {
            // QR
            while (true) {
                int m_ = lend;
                if (l != lend) {
                    for (int mi = l; mi >= lend+1; --mi) {
                        float em = e[mi-1];
                        float tst = em*em;
                        if (tst <= (SEPS2*fabsf(d[mi]))*fabsf(d[mi-1]) + SSAFMIN) { m_ = mi; break; }
                    }
                }
                if (m_ > lend) e[m_-1] = 0.0f;
                float p = d[l];
                if (m_ == l) {
                    d[l] = p; l = l - 1;
                    if (l >= lend) continue; else break;
                }
                if (m_ == l - 1) {
                    float rt1, rt2, cc, ss;
                    slaev2_(d[l-1], e[l-1], d[l], &rt1, &rt2, &cc, &ss);
                    for (int i = 1; i <= 3; ++i) {
                        float tmp = z[i][l];
                        z[i][l]   = cc*tmp - ss*z[i][l-1];
                        z[i][l-1] = ss*tmp + cc*z[i][l-1];
                    }
                    d[l-1] = rt1; d[l] = rt2; e[l-1] = 0.0f;
                    l = l - 2;
                    if (l >= lend) continue; else break;
                }
                if (jtot == nmaxit) break;
                jtot++;
                float g = (d[l-1] - p) / (2.0f*e[l-1]);
                float r = slapy2(g, 1.0f);
                g = d[m_] - p + (e[l-1] / (g + f_sign(r, g)));
                float s = 1.0f, c = 1.0f;
                p = 0.0f;
                for (int i = m_; i <= l-1; ++i) {
                    float f = s*e[i];
                    float b = c*e[i];
                    slartg_(g, f, &c, &s, &r);
                    if (i != m_) e[i-1] = r;
                    g = d[i] - p;
                    r = (d[i+1] - g)*s + (2.0f*c)*b;
                    p = s*r;
                    d[i] = g + p;
                    g = c*r - b;
                    cw[i] = c; sw[i] = s;
                }
                for (int j = m_; j <= l-1; ++j) {
                    float cc = cw[j], ss = sw[j];
                    for (int i = 1; i <= 3; ++i) {
                        float tmp = z[i][j+1];
                        z[i][j+1] = cc*tmp - ss*z[i][j];
                        z[i][j]   = ss*tmp + cc*z[i][j];
                    }
                }
                d[l] = d[l] - p;
                e[l-1] = g;
            }
        }
    }
    for (int ii = 2; ii <= 3; ++ii) {
        int i = ii - 1, k = i;
        float p = d[i];
        for (int j = ii; j <= 3; ++j) if (d[j] < p) { k = j; p = d[j]; }
        if (k != i) {
            d[k] = d[i]; d[i] = p;
            for (int r2 = 1; r2 <= 3; ++r2) {
                float t = z[r2][i]; z[r2][i] = z[r2][k]; z[r2][k] = t;
            }
        }
    }
    nv[0] = z[1][1]; nv[1] = z[2][1]; nv[2] = z[3][1];
}

// Shared epilogue math: covariance of the sorted 10-neighborhood + eigh.
__device__ void normal_compute(const float4* __restrict__ cl,
                               const unsigned long long keys[KNN],
                               float nv[3])
{
#pragma clang fp contract(off)
    float px[KNN], py[KNN], pz[KNN];
    float sx = 0.f, sy = 0.f, sz = 0.f;
    #pragma unroll
    for (int s = 0; s < KNN; ++s) {
        int ni = (int)(unsigned)(keys[s] & 0xFFFFFFFFull);
        float4 np = cl[ni];
        px[s] = np.x; py[s] = np.y; pz[s] = np.z;
        sx = sx + px[s]; sy = sy + py[s]; sz = sz + pz[s];
    }
    float mx = sx / 10.0f, my = sy / 10.0f, mz = sz / 10.0f;
    float c00=0.f,c01=0.f,c02=0.f,c11=0.f,c12=0.f,c22=0.f;
    #pragma unroll
    for (int s = 0; s < KNN; ++s) {
        float dx = px[s]-mx, dy = py[s]-my, dz = pz[s]-mz;
        c00 = c00 + dx*dx; c01 = c01 + dx*dy; c02 = c02 + dx*dz;
        c11 = c11 + dy*dy; c12 = c12 + dy*dz; c22 = c22 + dz*dz;
    }
    c00 = c00/10.0f; c01 = c01/10.0f; c02 = c02/10.0f;
    c11 = c11/10.0f; c12 = c12/10.0f; c22 = c22/10.0f;
    eigh3_smallest(c00, c01, c02, c11, c12, c22, nv);
}

// candidate insert (strict u64 key compare == top_k (d, idx) tie semantics)
#define PROC(p) do { \
    float ddx = qx - (p).x, ddy = qy - (p).y, ddz = qz - (p).z; \
    float dd = fmaf(ddz, ddz, fmaf(ddy, ddy, ddx*ddx)); \
    unsigned long long key = \
        ((unsigned long long)__float_as_uint(dd) << 32) | \
        (unsigned)__float_as_int((p).w); \
    if (key < k9) { \
        unsigned long long ck = key; \
        _Pragma("unroll") \
        for (int s = 0; s < KNN; ++s) { \
            unsigned long long ok2 = keys[s]; \
            bool sw = ok2 > ck; \
            keys[s] = sw ? ck : ok2; \
            ck      = sw ? ok2 : ck; \
        } \
        k9 = keys[KNN-1]; \
        worst = __uint_as_float((unsigned)(k9 >> 32)); \
    } \
} while (0)

// stream a contiguous candidate segment [b, b+n) of S — 2 loads in flight
// (4-wide tried in R11: VGPR 48->68, scratch spills, WRITE_SIZE 2.2->12 MB,
//  knn_main 130->170 us. This kernel is at register capacity; keep 2-wide.)
#define SEGPROC(b, n) do { \
    int _j = (b), _je = (b) + (n); \
    for (; _j + 2 <= _je; _j += 2) { \
        float4 _p0 = cs[_j]; float4 _p1 = cs[_j+1]; \
        PROC(_p0); PROC(_p1); \
    } \
    if (_j < _je) { float4 _p0 = cs[_j]; PROC(_p0); } \
} while (0)

// ---------------------------------------------------------------------------
// Kernel D: grid 10-NN, 1 lane/query, static segment descriptors in named
// scalars — EXACT R12 configuration (measured best: 146 us; R13's widened
// phase-1 rows regressed to 166 us by streaming ~67% more unpruned
// candidates). Cube (9 rows at x+/-1) + complete rho=2 shell (16 rows +
// 18 isolated cells, AABB-pruned). Unresolved -> brute overflow WITH the
// partial-scan 10th-best key as a pruning bound for the brute pass.
// ---------------------------------------------------------------------------
__global__ __launch_bounds__(256) void knn_main_kernel(
    const float4* __restrict__ P4, const float4* __restrict__ S,
    const int2* __restrict__ combo, float* __restrict__ Nrm,
    int* __restrict__ ovf, unsigned long long* __restrict__ ovf_key,
    int* __restrict__ ovf_count)
{
    int tidg = blockIdx.x * 256 + threadIdx.x;  // 0..65535
    int pair = tidg >> 13;                      // 8 clouds
    int spos = tidg & (NN - 1);                 // sorted position
    const float4* __restrict__ cl = P4 + (size_t)pair * NN;
    const float4* __restrict__ cs = S  + (size_t)pair * NN;
    const int2*   __restrict__ cb = combo + (size_t)pair * NCELLS;

    float4 q = cs[spos];
    float qx = q.x, qy = q.y, qz = q.z;
    int qi = __float_as_int(q.w);               // original index in cloud
    int qcx = cellc(qx), qcy = cellc(qy), qcz = cellc(qz);

    unsigned long long keys[KNN];
    #pragma unroll
    for (int s = 0; s < KNN; ++s) keys[s] = 0xFFFFFFFFFFFFFFFFull;
    unsigned long long k9 = keys[KNN-1];
    float worst = __uint_as_float(0xFFFFFFFFu); // NaN: all strict-> tests false

    // ---- phase 1: rho<=1 cube, 9 row-ranges, loads in named scalars ----
    int x0 = max(qcx - 1, 0), x1 = min(qcx + 1, G - 1);
#define P1LOAD(i, DZ, DY) \
    int rb##i = 0, re##i = 0; \
    { int zz = qcz + (DZ), yy = qcy + (DY); \
      if ((unsigned)zz < G && (unsigned)yy < G) { \
          int cbase = (zz*G + yy)*G; \
          int2 a = cb[cbase + x0]; \
          int2 b = cb[cbase + x1]; \
          rb##i = a.x; re##i = b.x + b.y; } }
    P1LOAD(0,-1,-1) P1LOAD(1,-1,0) P1LOAD(2,-1,1)
    P1LOAD(3, 0,-1) P1LOAD(4, 0,0) P1LOAD(5, 0,1)
    P1LOAD(6, 1,-1) P1LOAD(7, 1,0) P1LOAD(8, 1,1)
#undef P1LOAD
#define P1GO(i) SEGPROC(rb##i, re##i - rb##i);
    P1GO(0) P1GO(1) P1GO(2) P1GO(3) P1GO(4) P1GO(5) P1GO(6) P1GO(7) P1GO(8)
#undef P1GO

    // ---- phase 2: the complete rho=2 shell (skipped iff H^2 > worst) ----
    bool skip = (H*H > worst);                  // NaN-safe: NaN -> walk shell
    {
        int xs0 = max(qcx - 2, 0), xs1 = min(qcx + 2, G - 1);
        // 16 full rows: max(|dz|,|dy|) == 2
#define S2ROW(i, DZ, DY) \
        int sb##i = 0, sn##i = 0; \
        if (!skip) { int zz = qcz + (DZ), yy = qcy + (DY); \
          if ((unsigned)zz < G && (unsigned)yy < G) { \
              float loy = fmaf((float)yy, H, GRID_LO); \
              float loz = fmaf((float)zz, H, GRID_LO); \
              float py = fmaxf(0.0f, fmaxf(loy - qy, qy - (loy + H))); \
              float pz = fmaxf(0.0f, fmaxf(loz - qz, qz - (loz + H))); \
              float pyz = fmaf(pz, pz, py*py); \
              if (!(pyz > worst)) { \
                  int cbase = (zz*G + yy)*G; \
                  int2 a = cb[cbase + xs0]; \
                  int2 b = cb[cbase + xs1]; \
                  sb##i = a.x; sn##i = (b.x + b.y) - a.x; } } }
        S2ROW( 0,-2,-2) S2ROW( 1,-2,-1) S2ROW( 2,-2, 0) S2ROW( 3,-2, 1) S2ROW( 4,-2, 2)
        S2ROW( 5, 2,-2) S2ROW( 6, 2,-1) S2ROW( 7, 2, 0) S2ROW( 8, 2, 1) S2ROW( 9, 2, 2)
        S2ROW(10,-1,-2) S2ROW(11,-1, 2) S2ROW(12, 0,-2) S2ROW(13, 0, 2)
        S2ROW(14, 1,-2) S2ROW(15, 1, 2)
#undef S2ROW
        // 18 isolated cells: |dz|<=1, |dy|<=1, dx = +/-2 (bounds-checked)
#define S2CELL(i, DZ, DY, DX) \
        int tb##i = 0, tn##i = 0; \
        if (!skip) { int zz = qcz + (DZ), yy = qcy + (DY), xx = qcx + (DX); \
          if ((unsigned)zz < G && (unsigned)yy < G && (unsigned)xx < G) { \
              float lox = fmaf((float)xx, H, GRID_LO); \
              float loy = fmaf((float)yy, H, GRID_LO); \
              float loz = fmaf((float)zz, H, GRID_LO); \
              float px = fmaxf(0.0f, fmaxf(lox - qx, qx - (lox + H))); \
              float py = fmaxf(0.0f, fmaxf(loy - qy, qy - (loy + H))); \
              float pz = fmaxf(0.0f, fmaxf(loz - qz, qz - (loz + H))); \
              float m2 = fmaf(pz, pz, fmaf(py, py, px*px)); \
              if (!(m2 > worst)) { \
                  int2 a = cb[(zz*G + yy)*G + xx]; \
                  tb##i = a.x; tn##i = a.y; } } }
        S2CELL( 0,-1,-1,-2) S2CELL( 1,-1,-1, 2) S2CELL( 2,-1, 0,-2) S2CELL( 3,-1, 0, 2)
        S2CELL( 4,-1, 1,-2) S2CELL( 5,-1, 1, 2) S2CELL( 6, 0,-1,-2) S2CELL( 7, 0,-1, 2)
        S2CELL( 8, 0, 0,-2) S2CELL( 9, 0, 0, 2) S2CELL(10, 0, 1,-2) S2CELL(11, 0, 1, 2)
        S2CELL(12, 1,-1,-2) S2CELL(13, 1,-1, 2) S2CELL(14, 1, 0,-2) S2CELL(15, 1, 0, 2)
        S2CELL(16, 1, 1,-2) S2CELL(17, 1, 1, 2)
#undef S2CELL
#define S2GO(i) SEGPROC(sb##i, sn##i);
        S2GO(0) S2GO(1) S2GO(2) S2GO(3) S2GO(4) S2GO(5) S2GO(6) S2GO(7)
        S2GO(8) S2GO(9) S2GO(10) S2GO(11) S2GO(12) S2GO(13) S2GO(14) S2GO(15)
#undef S2GO
#define S2CGO(i) SEGPROC(tb##i, tn##i);
        S2CGO(0) S2CGO(1) S2CGO(2) S2CGO(3) S2CGO(4) S2CGO(5) S2CGO(6) S2CGO(7)
        S2CGO(8) S2CGO(9) S2CGO(10) S2CGO(11) S2CGO(12) S2CGO(13) S2CGO(14)
        S2CGO(15) S2CGO(16) S2CGO(17)
#undef S2CGO
    }

    // resolved iff cells beyond the rho<=2 region (gap >= 2H) cannot contribute
    float bf = (float)RCAP * H;
    bool resolved = (bf*bf > worst);            // strict; NaN (unfilled) -> false
    if (resolved) {
        float nv[3];
        normal_compute(cl, keys, nv);
        float* o = Nrm + ((size_t)pair*NN + qi)*3;
        o[0] = nv[0]; o[1] = nv[1]; o[2] = nv[2];
    } else {
        int pos = atomicAdd(ovf_count, 1);
        ovf[pos] = (pair << 13) | qi;
        ovf_key[pos] = k9;      // partial 10th-best: valid upper bound on true
    }                           // 10th key (subset 10th >= full-set 10th)
}

// ---------------------------------------------------------------------------
// Kernel D2: brute-force overflow, one query per block (256 thr = 4 waves).
// The main-phase 10th-best key is a proven upper bound on the true 10th
// key, so candidates with dd > bound_d skip the insert chain entirely.
// bound_d = NaN for unfilled lists -> gate passes everything (NaN-safe).
// R14: scan MLP widened 2->4 loads in flight (stride 1024, 8 outer iters)
// — brute has register headroom (VGPR 56), unlike knn_main.
// ---------------------------------------------------------------------------
#define BRUTE_BLOCKS 4096
__global__ __launch_bounds__(256) void brute_kernel(
    const float4* __restrict__ P4, const int* __restrict__ ovf,
    const unsigned long long* __restrict__ ovf_key,
    const int* __restrict__ ovf_count, float* __restrict__ Nrm)
{
    __shared__ unsigned long long wl[4][KNN];
    int tid = threadIdx.x;
    int lane = tid & 63;
    int wid = tid >> 6;
    int count = *ovf_count;

    for (int oi = blockIdx.x; oi < count; oi += BRUTE_BLOCKS) {
        int rec = ovf[oi];
        unsigned long long bound = ovf_key[oi];
        float bound_d = __uint_as_float((unsigned)(bound >> 32)); // NaN if unfilled
        int pair = rec >> 13;
        int qi = rec & (NN - 1);
        const float4* __restrict__ cl = P4 + (size_t)pair * NN;
        float4 q = cl[qi];
        float qx = q.x, qy = q.y, qz = q.z;

        unsigned long long keys[KNN];
        #pragma unroll
        for (int s = 0; s < KNN; ++s) keys[s] = 0xFFFFFFFFFFFFFFFFull;
        unsigned long long k9 = keys[KNN-1];

        // per-lane scan with bound gate; ties at dd==bound_d pass (exact)
#define BPROC(p, jj) do { \
        float ddx = qx - (p).x, ddy = qy - (p).y, ddz = qz - (p).z; \
        float dd = fmaf(ddz, ddz, fmaf(ddy, ddy, ddx*ddx)); \
        if (!(dd > bound_d)) { \
            unsigned long long key = \
                ((unsigned long long)__float_as_uint(dd) << 32) | (unsigned)(jj); \
            if (key < k9) { \
                unsigned long long ck = key; \
                _Pragma("unroll") \
                for (int s = 0; s < KNN; ++s) { \
                    unsigned long long ok2 = keys[s]; \
                    bool sw = ok2 > ck; \
                    keys[s] = sw ? ck : ok2; \
                    ck      = sw ? ok2 : ck; \
                } \
                k9 = keys[KNN-1]; \
            } \
        } \
    } while (0)
        #pragma unroll 1
        for (int j = tid; j < NN; j += 1024) {  // 8 iterations, 4 loads each
            float4 p0 = cl[j];
            float4 p1 = cl[j + 256];
            float4 p2 = cl[j + 512];
            float4 p3 = cl[j + 768];
            BPROC(p0, j);
            BPROC(p1, j + 256);
            BPROC(p2, j + 512);
            BPROC(p3, j + 768);
        }
#undef BPROC

        // in-wave tree merge -> every lane holds its wave's top-10
        #pragma unroll
        for (int m = 1; m < 64; m <<= 1) {
            unsigned long long other[KNN];
            #pragma unroll
            for (int s = 0; s < KNN; ++s)
                other[s] = __shfl_xor(keys[s], m);  // snapshot before inserts
            #pragma unroll
            for (int s = 0; s < KNN; ++s) {
                unsigned long long key = other[s];
                if (key < k9) {
                    unsigned long long ck = key;
                    #pragma unroll
                    for (int t = 0; t < KNN; ++t) {
                        unsigned long long ok2 = keys[t];
                        bool sw = ok2 > ck;
                        keys[t] = sw ? ck : ok2;
                        ck      = sw ? ok2 : ck;
                    }
                    k9 = keys[KNN-1];
                }
            }
        }

        // cross-wave merge via LDS (4 sorted lists)
        if (lane == 0) {
            #pragma unroll
            for (int s = 0; s < KNN; ++s) wl[wid][s] = keys[s];
        }
        __syncthreads();
        if (wid == 0) {
            for (int w2 = 1; w2 < 4; ++w2) {
                #pragma unroll
                for (int s = 0; s < KNN; ++s) {
                    unsigned long long key = wl[w2][s];
                    if (key >= k9) break;       // lists sorted ascending
                    unsigned long long ck = key;
                    #pragma unroll
                    for (int t = 0; t < KNN; ++t) {
                        unsigned long long ok2 = keys[t];
                        bool sw = ok2 > ck;
                        keys[t] = sw ? ck : ok2;
                        ck      = sw ? ok2 : ck;
                    }
                    k9 = keys[KNN-1];
                }
            }
            if (lane == 0) {
                float nv[3];
                normal_compute(cl, keys, nv);
                float* o = Nrm + ((size_t)pair*NN + qi)*3;
                o[0] = nv[0]; o[1] = nv[1]; o[2] = nv[2];
            }
        }
        __syncthreads();                        // protect wl for next query
    }
}

// ---------------------------------------------------------------------------
// Kernel E: per-point 1 - cos, block partial sums, device-scope atomic
// accumulate; last block writes the mean.
// ---------------------------------------------------------------------------
__global__ __launch_bounds__(256) void loss_final_kernel(
    const float* __restrict__ Nrm, float* __restrict__ accum,
    unsigned* __restrict__ counter, float* __restrict__ out)
{
    int tid = threadIdx.x;
    int i = blockIdx.x * 256 + tid;            // 0..BN-1
    const float* g = Nrm + (size_t)i*3;
    const float* p = Nrm + ((size_t)BN + i)*3;
    float gx=g[0], gy=g[1], gz=g[2];
    float hx=p[0], hy=p[1], hz=p[2];
    float dot = fmaf(gx,hx,fmaf(gy,hy,gz*hz));
    float ng  = sqrtf(fmaf(gx,gx,fmaf(gy,gy,gz*gz)));
    float nh  = sqrtf(fmaf(hx,hx,fmaf(hy,hy,hz*hz)));
    float den = fmaxf(ng*nh, 1e-8f);
    float v = 1.0f - dot/den;

    __shared__ float red[256];
    red[tid] = v;
    __syncthreads();
    for (int s = 128; s > 0; s >>= 1) {
        if (tid < s) red[tid] += red[tid+s];
        __syncthreads();
    }
    if (tid == 0) {
        atomicAdd(accum, red[0]);
        __threadfence();
        unsigned old = atomicAdd(counter, 1u);
        if (old == (unsigned)(BN/256 - 1)) {
            float tot = atomicAdd(accum, 0.0f);
            out[0] = tot * (1.0f/(float)BN);
        }
    }
}

// ---------------------------------------------------------------------------
extern "C" void kernel_launch(void* const* d_in, const int* in_sizes, int n_in,
                              void* d_out, int out_size, void* d_ws, size_t ws_size,
                              hipStream_t stream)
{
    (void)in_sizes; (void)n_in; (void)out_size; (void)ws_size;
    const float*    gt   = (const float*)d_in[0];
    const float*    pred = (const float*)d_in[1];
    const unsigned* idxw = (const unsigned*)d_in[2];
    float* out = (float*)d_out;

    char* w = (char*)d_ws;
    float4* P4   = (float4*)w;                         w += (size_t)2*BN*16;   // 1 MB
    float4* S    = (float4*)w;                         w += (size_t)2*BN*16;   // 1 MB
    int*    hist = (int*)w;                            w += (size_t)8*NCELLS*4;   // 1 MB
    int2*   combo = (int2*)w;                          w += (size_t)8*NCELLS*8;   // 2 MB
    float*  Nrm  = (float*)w;                          w += (size_t)2*BN*3*4;  // 0.75 MB
    float*  accum = (float*)w;                         w += 16;
    unsigned* counter = (unsigned*)(accum + 1);
    int*    ovf_count = (int*)(accum + 2);
    int*    ovf  = (int*)w;                            w += (size_t)2*BN*4;    // 0.25 MB
    unsigned long long* ovf_key = (unsigned long long*)w;  w += (size_t)2*BN*8; // 0.5 MB

    hipMemsetAsync(hist, 0, (size_t)8*NCELLS*4, stream);
    hipLaunchKernelGGL(prep_kernel,    dim3(2*BN/256), dim3(256),  0, stream,
                       gt, pred, idxw, P4, hist, accum, counter, ovf_count);
    hipLaunchKernelGGL(scan_kernel,    dim3(8),        dim3(1024), 0, stream,
                       hist, combo);
    hipLaunchKernelGGL(scatter_kernel, dim3(2*BN/256), dim3(256),  0, stream,
                       P4, hist, combo, S);
    hipLaunchKernelGGL(knn_main_kernel, dim3(2*BN/256), dim3(256), 0, stream,
                       P4, S, combo, Nrm, ovf, ovf_key, ovf_count);
    hipLaunchKernelGGL(brute_kernel,   dim3(BRUTE_BLOCKS), dim3(256), 0, stream,
                       P4, ovf, ovf_key, ovf_count, Nrm);
    hipLaunchKernelGGL(loss_final_kernel, dim3(BN/256), dim3(256), 0, stream,
                       Nrm, accum, counter, out);
}